// Round 7
// baseline (116.535 us; speedup 1.0000x reference)
//
#include <hip/hip_runtime.h>

// Tiny ViT forward, B=8192, fp32. Wave-per-IMAGE-PAIR (A,B). Weight
// phases (embed/qkv/proj/FF/head/LN) are DUAL-SCALAR streams: per
// weight, two v_fma_f32 with the weight as a direct SGPR operand (no
// fx2 splat -> no risk of v_mov splat materialization). Attention stays
// fully packed vector x vector (v_pk_fma_f32) with K/V stored as
// interleaved (A,B) pairs in per-wave LDS (broadcast reads, no
// barriers), now with even/odd dual accumulator banks for ILP.
// One-pass softmax without max subtraction (scores ~0.06 std).

typedef float fx2 __attribute__((ext_vector_type(2)));

#define T_TOK    50
#define WAVES_PB 4
#define THREADS  (WAVES_PB * 64)
#define KVSTRIDE 36                  // floats per token: 32 + 4 pad
#define SCALE    0.35355339059327373f   // 8^-0.5

#if __has_builtin(__builtin_amdgcn_exp2f)
  #define FASTEXP(x) __builtin_amdgcn_exp2f(x)
  #define QSCALE (SCALE * 1.4426950408889634f)   // fold log2(e) into q
#else
  #define FASTEXP(x) __expf(x)
  #define QSCALE SCALE
#endif

__device__ __forceinline__ fx2 lo4(float4 u)  { return (fx2){u.x, u.y}; }
__device__ __forceinline__ fx2 hi4(float4 u)  { return (fx2){u.z, u.w}; }
__device__ __forceinline__ fx2 expboth(fx2 v) {
    return (fx2){FASTEXP(v.x), FASTEXP(v.y)};
}

__global__ __launch_bounds__(THREADS) void vit_fwd(
    const float* __restrict__ images, const float* __restrict__ cls,
    const float* __restrict__ linW,
    const float* __restrict__ g1,  const float* __restrict__ be1,
    const float* __restrict__ Wq,  const float* __restrict__ Wk,
    const float* __restrict__ Wv,  const float* __restrict__ Pw,
    const float* __restrict__ Pb,  const float* __restrict__ g2,
    const float* __restrict__ be2, const float* __restrict__ W1,
    const float* __restrict__ bb1, const float* __restrict__ W2,
    const float* __restrict__ bb2, const float* __restrict__ mlpW,
    const float* __restrict__ mlpb,
    float* __restrict__ out, int B)
{
    __shared__ float kv[WAVES_PB * T_TOK * KVSTRIDE];   // 28800 B

    const int lane = threadIdx.x & 63;
    const int wid  = threadIdx.x >> 6;
    const int pair = blockIdx.x * WAVES_PB + wid;   // wave-uniform
    const int gA   = pair * 2;
    if (gA >= B) return;
    const bool hasB = (gA + 1) < B;
    const int gB   = hasB ? gA + 1 : gA;
    const int t    = (lane < T_TOK) ? lane : (T_TOK - 1);
    float* __restrict__ kvw = kv + wid * (T_TOK * KVSTRIDE);

    // ---- patch embed + positional (pos depends only on t: shared) ----
    float xa[8], xb[8];
    {
        const float FR[4] = {1.f, 0.1f, 0.01f, 0.001f};
        float pos[8];
        #pragma unroll
        for (int j = 0; j < 8; ++j) {
            float arg = (float)t * FR[j >> 1];
            pos[j] = (j & 1) ? __cosf(arg) : __sinf(arg);
        }
        if (t == 0) {
            #pragma unroll
            for (int e = 0; e < 8; ++e) { xa[e] = cls[e] + pos[e]; xb[e] = xa[e]; }
        } else {
            const int p = t - 1, pr = p / 7, pc = p - pr * 7;
            const size_t off = (size_t)pr * 112 + pc * 4;
            const float* ibA = images + (size_t)gA * 784 + off;
            const float* ibB = images + (size_t)gB * 784 + off;
            float pa[16], pb[16];
            #pragma unroll
            for (int r = 0; r < 4; ++r) {
                float4 ua = *reinterpret_cast<const float4*>(ibA + r * 28);
                float4 ub = *reinterpret_cast<const float4*>(ibB + r * 28);
                pa[r*4+0]=ua.x; pa[r*4+1]=ua.y; pa[r*4+2]=ua.z; pa[r*4+3]=ua.w;
                pb[r*4+0]=ub.x; pb[r*4+1]=ub.y; pb[r*4+2]=ub.z; pb[r*4+3]=ub.w;
            }
            #pragma unroll
            for (int e = 0; e < 8; ++e) {
                float aA = pos[e], aB = pos[e];
                #pragma unroll
                for (int i = 0; i < 16; ++i) {
                    const float w = linW[e*16 + i];
                    aA += pa[i] * w; aB += pb[i] * w;
                }
                xa[e] = aA; xb[e] = aB;
            }
        }
    }

    #pragma unroll 1
    for (int blk = 0; blk < 4; ++blk) {
        const int w8 = blk * 8, w64 = blk * 64, w256 = blk * 256, w32 = blk * 32;

        // ---- LN1 (dual scalar) ----
        float hA[8], hB[8];
        {
            float muA = 0.f, muB = 0.f;
            #pragma unroll
            for (int d = 0; d < 8; ++d) { muA += xa[d]; muB += xb[d]; }
            muA *= 0.125f; muB *= 0.125f;
            float vA = 0.f, vB = 0.f;
            #pragma unroll
            for (int d = 0; d < 8; ++d) {
                float dA = xa[d] - muA, dB = xb[d] - muB;
                vA += dA * dA; vB += dB * dB;
            }
            const float rA = rsqrtf(vA * 0.125f + 1e-5f);
            const float rB = rsqrtf(vB * 0.125f + 1e-5f);
            #pragma unroll
            for (int d = 0; d < 8; ++d) {
                const float g = g1[w8 + d], b = be1[w8 + d];
                hA[d] = (xa[d] - muA) * rA * g + b;
                hB[d] = (xb[d] - muB) * rB * g + b;
            }
        }

        // ---- q,k,v (dual scalar, SGPR weights) ----
        fx2 q[8];
        float kA[8], kB[8], vvA[8], vvB[8];
        #pragma unroll
        for (int e = 0; e < 8; ++e) {
            float aqA=0.f, aqB=0.f, akA=0.f, akB=0.f, avA=0.f, avB=0.f;
            #pragma unroll
            for (int d = 0; d < 8; ++d) {
                const float wq = Wq[w64 + e*8 + d];
                const float wk = Wk[w64 + e*8 + d];
                const float wv = Wv[w64 + e*8 + d];
                aqA += hA[d]*wq; aqB += hB[d]*wq;
                akA += hA[d]*wk; akB += hB[d]*wk;
                avA += hA[d]*wv; avB += hB[d]*wv;
            }
            q[e] = (fx2){aqA * QSCALE, aqB * QSCALE};
            kA[e] = akA; kB[e] = akB; vvA[e] = avA; vvB[e] = avB;
        }
        {   // K pairs then V pairs, interleaved [kA0,kB0,kA1,kB1,...]
            float* kvp = kvw + t * KVSTRIDE;
            *reinterpret_cast<float4*>(kvp +  0) = make_float4(kA[0],kB[0],kA[1],kB[1]);
            *reinterpret_cast<float4*>(kvp +  4) = make_float4(kA[2],kB[2],kA[3],kB[3]);
            *reinterpret_cast<float4*>(kvp +  8) = make_float4(kA[4],kB[4],kA[5],kB[5]);
            *reinterpret_cast<float4*>(kvp + 12) = make_float4(kA[6],kB[6],kA[7],kB[7]);
            *reinterpret_cast<float4*>(kvp + 16) = make_float4(vvA[0],vvB[0],vvA[1],vvB[1]);
            *reinterpret_cast<float4*>(kvp + 20) = make_float4(vvA[2],vvB[2],vvA[3],vvB[3]);
            *reinterpret_cast<float4*>(kvp + 24) = make_float4(vvA[4],vvB[4],vvA[5],vvB[5]);
            *reinterpret_cast<float4*>(kvp + 28) = make_float4(vvA[6],vvB[6],vvA[7],vvB[7]);
        }

        // ---- attention: packed, broadcast LDS reads, even/odd acc banks ----
        fx2 l0e = {0,0}, l1e = {0,0}, l0o = {0,0}, l1o = {0,0};
        fx2 ace[8], aco[8];
        #pragma unroll
        for (int d = 0; d < 8; ++d) { ace[d] = (fx2){0,0}; aco[d] = (fx2){0,0}; }
        #pragma unroll 2
        for (int s = 0; s < T_TOK; s += 2) {
            const float* sp0 = kvw + s * KVSTRIDE;
            const float* sp1 = sp0 + KVSTRIDE;
            float4 ek01 = *reinterpret_cast<const float4*>(sp0 +  0);
            float4 ek23 = *reinterpret_cast<const float4*>(sp0 +  4);
            float4 ek45 = *reinterpret_cast<const float4*>(sp0 +  8);
            float4 ek67 = *reinterpret_cast<const float4*>(sp0 + 12);
            float4 ok01 = *reinterpret_cast<const float4*>(sp1 +  0);
            float4 ok23 = *reinterpret_cast<const float4*>(sp1 +  4);
            float4 ok45 = *reinterpret_cast<const float4*>(sp1 +  8);
            float4 ok67 = *reinterpret_cast<const float4*>(sp1 + 12);
            fx2 de0 = q[0]*lo4(ek01) + q[1]*hi4(ek01) + q[2]*lo4(ek23) + q[3]*hi4(ek23);
            fx2 de1 = q[4]*lo4(ek45) + q[5]*hi4(ek45) + q[6]*lo4(ek67) + q[7]*hi4(ek67);
            fx2 do0 = q[0]*lo4(ok01) + q[1]*hi4(ok01) + q[2]*lo4(ok23) + q[3]*hi4(ok23);
            fx2 do1 = q[4]*lo4(ok45) + q[5]*hi4(ok45) + q[6]*lo4(ok67) + q[7]*hi4(ok67);
            fx2 pe0 = expboth(de0), pe1 = expboth(de1);
            fx2 po0 = expboth(do0), po1 = expboth(do1);
            l0e += pe0; l1e += pe1; l0o += po0; l1o += po1;
            float4 ev01 = *reinterpret_cast<const float4*>(sp0 + 16);
            float4 ev23 = *reinterpret_cast<const float4*>(sp0 + 20);
            float4 ev45 = *reinterpret_cast<const float4*>(sp0 + 24);
            float4 ev67 = *reinterpret_cast<const float4*>(sp0 + 28);
            float4 ov01 = *reinterpret_cast<const float4*>(sp1 + 16);
            float4 ov23 = *reinterpret_cast<const float4*>(sp1 + 20);
            float4 ov45 = *reinterpret_cast<const float4*>(sp1 + 24);
            float4 ov67 = *reinterpret_cast<const float4*>(sp1 + 28);
            ace[0] += pe0*lo4(ev01); ace[1] += pe0*hi4(ev01);
            ace[2] += pe0*lo4(ev23); ace[3] += pe0*hi4(ev23);
            ace[4] += pe1*lo4(ev45); ace[5] += pe1*hi4(ev45);
            ace[6] += pe1*lo4(ev67); ace[7] += pe1*hi4(ev67);
            aco[0] += po0*lo4(ov01); aco[1] += po0*hi4(ov01);
            aco[2] += po0*lo4(ov23); aco[3] += po0*hi4(ov23);
            aco[4] += po1*lo4(ov45); aco[5] += po1*hi4(ov45);
            aco[6] += po1*lo4(ov67); aco[7] += po1*hi4(ov67);
        }
        float oA[8], oB[8];
        {
            fx2 l0 = l0e + l0o, l1 = l1e + l1o;
            const float r0A = 1.f / l0.x, r0B = 1.f / l0.y;
            const float r1A = 1.f / l1.x, r1B = 1.f / l1.y;
            #pragma unroll
            for (int d = 0; d < 4; ++d) {
                fx2 a = ace[d] + aco[d];
                fx2 b = ace[d+4] + aco[d+4];
                oA[d]   = a.x * r0A; oB[d]   = a.y * r0B;
                oA[d+4] = b.x * r1A; oB[d+4] = b.y * r1B;
            }
        }

        // ---- proj + residual (dual scalar) ----
        float xnA[8], xnB[8];
        #pragma unroll
        for (int e = 0; e < 8; ++e) {
            float aA = Pb[w8 + e], aB = aA;
            #pragma unroll
            for (int d = 0; d < 8; ++d) {
                const float w = Pw[w64 + e*8 + d];
                aA += oA[d] * w; aB += oB[d] * w;
            }
            xnA[e] = xa[e] + aA; xnB[e] = xb[e] + aB;
        }

        // ---- LN2 (dual scalar) ----
        float h2A[8], h2B[8];
        {
            float muA = 0.f, muB = 0.f;
            #pragma unroll
            for (int d = 0; d < 8; ++d) { muA += xnA[d]; muB += xnB[d]; }
            muA *= 0.125f; muB *= 0.125f;
            float vA = 0.f, vB = 0.f;
            #pragma unroll
            for (int d = 0; d < 8; ++d) {
                float dA = xnA[d] - muA, dB = xnB[d] - muB;
                vA += dA * dA; vB += dB * dB;
            }
            const float rA = rsqrtf(vA * 0.125f + 1e-5f);
            const float rB = rsqrtf(vB * 0.125f + 1e-5f);
            #pragma unroll
            for (int d = 0; d < 8; ++d) {
                const float g = g2[w8 + d], b = be2[w8 + d];
                h2A[d] = (xnA[d] - muA) * rA * g + b;
                h2B[d] = (xnB[d] - muB) * rB * g + b;
            }
        }

        // ---- FF (dual scalar) ----
        {
            float accA[8], accB[8];
            #pragma unroll
            for (int d = 0; d < 8; ++d) { accA[d] = 0.f; accB[d] = 0.f; }
            #pragma unroll 4
            for (int f = 0; f < 32; ++f) {
                float aA = bb1[w32 + f], aB = aA;
                #pragma unroll
                for (int d = 0; d < 8; ++d) {
                    const float w = W1[w256 + f*8 + d];
                    aA += h2A[d] * w; aB += h2B[d] * w;
                }
                aA = fmaxf(aA, 0.f); aB = fmaxf(aB, 0.f);
                #pragma unroll
                for (int d = 0; d < 8; ++d) {
                    const float w = W2[w256 + d*32 + f];
                    accA[d] += aA * w; accB[d] += aB * w;
                }
            }
            #pragma unroll
            for (int d = 0; d < 8; ++d) {
                const float b = bb2[w8 + d];
                xa[d] = xnA[d] + accA[d] + b;
                xb[d] = xnB[d] + accB[d] + b;
            }
        }
    }

    // ---- classification head: lane 0 (token 0), both images ----
    if (lane == 0) {
        float lgA[10], lgB[10];
        float mxA = -1e30f, mxB = -1e30f;
        #pragma unroll
        for (int c = 0; c < 10; ++c) {
            float aA = mlpb[c], aB = aA;
            #pragma unroll
            for (int d = 0; d < 8; ++d) {
                const float w = mlpW[c*8 + d];
                aA += xa[d] * w; aB += xb[d] * w;
            }
            lgA[c] = aA; lgB[c] = aB;
            mxA = fmaxf(mxA, aA); mxB = fmaxf(mxB, aB);
        }
        float sA = 0.f, sB = 0.f;
        #pragma unroll
        for (int c = 0; c < 10; ++c) {
            lgA[c] = __expf(lgA[c] - mxA); sA += lgA[c];
            lgB[c] = __expf(lgB[c] - mxB); sB += lgB[c];
        }
        const float rA = 1.f / sA, rB = 1.f / sB;
        #pragma unroll
        for (int c = 0; c < 10; ++c) {
            out[(size_t)gA*10 + c] = lgA[c] * rA;
            if (hasB) out[(size_t)gB*10 + c] = lgB[c] * rB;
        }
    }
}

extern "C" void kernel_launch(void* const* d_in, const int* in_sizes, int n_in,
                              void* d_out, int out_size, void* d_ws, size_t ws_size,
                              hipStream_t stream) {
    const int B = in_sizes[0] / 784;
    const int pairs = (B + 1) / 2;
    const int nblk = (pairs + WAVES_PB - 1) / WAVES_PB;
    vit_fwd<<<nblk, THREADS, 0, stream>>>(
        (const float*)d_in[0],  (const float*)d_in[1],  (const float*)d_in[2],
        (const float*)d_in[3],  (const float*)d_in[4],  (const float*)d_in[5],
        (const float*)d_in[6],  (const float*)d_in[7],  (const float*)d_in[8],
        (const float*)d_in[9],  (const float*)d_in[10], (const float*)d_in[11],
        (const float*)d_in[12], (const float*)d_in[13], (const float*)d_in[14],
        (const float*)d_in[15], (const float*)d_in[16], (const float*)d_in[17],
        (float*)d_out, B);
}